// Round 10
// baseline (197.947 us; speedup 1.0000x reference)
//
#include <hip/hip_runtime.h>

// WeightedAggEdge: node_feat = h@Wn^T; per-edge segment-softmax attention
// over fc_e(e) grouped by src node; outputs (node_feat, gamma * e_w).
//
// Round 10: round-6 structure (best: 154.3us) + round-9's verified
// transposed-MFMA epilogues (f32x4 stores) + k0 folded into consumers
// (k1/k4 self-convert weights from f32; kconv computes v in-wave).
// Plain loads (NT was neutral-negative), single denom + fused atomics.

constexpr int kNodes   = 50000;
constexpr int kEdges   = 800000;
constexpr int kNodeIn  = 128;
constexpr int kNodeOut = 64;
constexpr int kEdgeIn  = 64;
constexpr int kEdgeOut = 64;
#define NEG_SLOPE 0.01f

typedef __attribute__((ext_vector_type(8))) short short8;   // 8 bf16 = 4 VGPRs
typedef __attribute__((ext_vector_type(4))) short short4v;  // 4 bf16 = 8 B
typedef __attribute__((ext_vector_type(4))) float f32x4;

// ws layout (float index), all 16B-aligned:
//   [0, 50000)           s_n
//   [50048, 100048)      denom
//   [100096, 900096)     ex
//   [900096, +25.6M)     e_bf16 (kEdges*64 shorts)
constexpr int kOffSn    = 0;
constexpr int kOffDenom = 50048;
constexpr int kOffEx    = 100096;
constexpr int kOffEbf   = 900096;

__device__ inline short f2bf(float x) {
    union { float f; unsigned u; } v; v.f = x;
    unsigned r = v.u + 0x7FFFu + ((v.u >> 16) & 1u);  // RNE
    return (short)(r >> 16);
}

// node_feat = h @ Wn^T via bf16 MFMA (transposed epilogue); one wave = 16 nodes.
// Wn fragments converted from f32 in-kernel (L2-hot, 32KB).
// Also: s_n[n] = dot(Wa[64:128], node_feat[n]); denom zero-init.
__global__ __launch_bounds__(256) void k1_mfma(
    const float* __restrict__ h, const float* __restrict__ Wn,
    const float* __restrict__ Wa, float* __restrict__ node_feat,
    float* __restrict__ s_n, float* __restrict__ denom) {
    const int lane = threadIdx.x & 63;
    const int l15  = lane & 15;
    const int lhi  = lane >> 4;
    const int n0   = blockIdx.x * 64 + (threadIdx.x >> 6) * 16;

    int gid = blockIdx.x * 256 + threadIdx.x;
    if (gid < kNodes) denom[gid] = 0.f;

    // A-fragments (Wn rows, converted f32->bf16): row = ct*16+l15, k = kt*32+lhi*8
    short8 Af[4][4];
    #pragma unroll
    for (int kt = 0; kt < 4; ++kt)
        #pragma unroll
        for (int ct = 0; ct < 4; ++ct) {
            const float* wrow = Wn + (ct * 16 + l15) * kNodeIn + kt * 32 + lhi * 8;
            f32x4 w0 = *reinterpret_cast<const f32x4*>(wrow);
            f32x4 w1 = *reinterpret_cast<const f32x4*>(wrow + 4);
            short8 af;
            af[0] = f2bf(w0[0]); af[1] = f2bf(w0[1]); af[2] = f2bf(w0[2]); af[3] = f2bf(w0[3]);
            af[4] = f2bf(w1[0]); af[5] = f2bf(w1[1]); af[6] = f2bf(w1[2]); af[7] = f2bf(w1[3]);
            Af[kt][ct] = af;
        }

    const int  arow   = n0 + l15;
    const bool rv     = arow < kNodes;
    const float* hrow = h + (size_t)arow * kNodeIn;

    f32x4 acc[4];
    #pragma unroll
    for (int ct = 0; ct < 4; ++ct) acc[ct] = (f32x4)(0.f);

    #pragma unroll
    for (int kt = 0; kt < 4; ++kt) {
        short8 bf;  // B: col = node (l15), k slice
        if (rv) {
            f32x4 t0 = *reinterpret_cast<const f32x4*>(hrow + kt * 32 + lhi * 8);
            f32x4 t1 = *reinterpret_cast<const f32x4*>(hrow + kt * 32 + lhi * 8 + 4);
            bf[0] = f2bf(t0[0]); bf[1] = f2bf(t0[1]); bf[2] = f2bf(t0[2]); bf[3] = f2bf(t0[3]);
            bf[4] = f2bf(t1[0]); bf[5] = f2bf(t1[1]); bf[6] = f2bf(t1[2]); bf[7] = f2bf(t1[3]);
        } else {
            #pragma unroll
            for (int j = 0; j < 8; ++j) bf[j] = 0;
        }
        #pragma unroll
        for (int ct = 0; ct < 4; ++ct)
            acc[ct] = __builtin_amdgcn_mfma_f32_16x16x32_bf16(Af[kt][ct], bf, acc[ct], 0, 0, 0);
    }

    // Transposed epilogue: lane owns node (n0+l15), channels ct*16 + lhi*4 + 0..3.
    float part = 0.f;
    #pragma unroll
    for (int ct = 0; ct < 4; ++ct) {
        f32x4 wa4 = *reinterpret_cast<const f32x4*>(Wa + 64 + ct * 16 + lhi * 4);
        part = fmaf(wa4[0], acc[ct][0], part);
        part = fmaf(wa4[1], acc[ct][1], part);
        part = fmaf(wa4[2], acc[ct][2], part);
        part = fmaf(wa4[3], acc[ct][3], part);
        if (rv)
            __builtin_nontemporal_store(acc[ct],
                reinterpret_cast<f32x4*>(node_feat + (size_t)arow * kNodeOut + ct * 16 + lhi * 4));
    }
    part += __shfl_xor(part, 16, 64);
    part += __shfl_xor(part, 32, 64);
    if (rv && lhi == 0) s_n[arow] = part;
}

// Coalesced streaming pass over e: 64 rows per block (4 iters x 16 rows).
// Prologue: each lane computes its 4 v-entries (v = We^T @ Wa[0:64]) via a
// 4-way c-split over the hi-lanes + shfl_xor(16/32) reduce.
// Main: thread t handles float4 #(t&15) of row; shfl-reduce dot; lane q==0
// finishes the logit (s_n gather, leaky, exp), stores ex, atomicAdd denom.
__global__ __launch_bounds__(256) void kconv(
    const float* __restrict__ e, const float* __restrict__ We,
    const float* __restrict__ Wa, const int* __restrict__ src,
    const float* __restrict__ s_n, float* __restrict__ denom,
    float* __restrict__ ex, short* __restrict__ ebf) {
    const int t   = threadIdx.x;
    const int q   = t & 15;         // float4 index within row
    const int rlo = t >> 4;         // row within 16-row group (block-wide)
    const int hi  = (t >> 4) & 3;   // wave-local high lanes
    const long base = (long)blockIdx.x * 64;

    // vv[j] = v[q*4+j] = sum_c Wa[c] * We[c][q*4+j]; c split 4 ways over hi.
    f32x4 vv = (f32x4)(0.f);
    #pragma unroll
    for (int cc = 0; cc < 16; ++cc) {
        int c = hi * 16 + cc;
        float wac = Wa[c];
        f32x4 w = *reinterpret_cast<const f32x4*>(We + c * kEdgeIn + q * 4);
        vv[0] = fmaf(wac, w[0], vv[0]);
        vv[1] = fmaf(wac, w[1], vv[1]);
        vv[2] = fmaf(wac, w[2], vv[2]);
        vv[3] = fmaf(wac, w[3], vv[3]);
    }
    #pragma unroll
    for (int j = 0; j < 4; ++j) {
        vv[j] += __shfl_xor(vv[j], 16, 64);
        vv[j] += __shfl_xor(vv[j], 32, 64);
    }

    #pragma unroll
    for (int it = 0; it < 4; ++it) {
        long r = base + it * 16 + rlo;
        f32x4 d = *(reinterpret_cast<const f32x4*>(e + r * kEdgeIn) + q);
        float part = d[0] * vv[0] + d[1] * vv[1] + d[2] * vv[2] + d[3] * vv[3];
        part += __shfl_xor(part, 1, 64);
        part += __shfl_xor(part, 2, 64);
        part += __shfl_xor(part, 4, 64);
        part += __shfl_xor(part, 8, 64);
        short4v o;
        o[0] = f2bf(d[0]); o[1] = f2bf(d[1]); o[2] = f2bf(d[2]); o[3] = f2bf(d[3]);
        *reinterpret_cast<short4v*>(ebf + r * kEdgeIn + q * 4) = o;
        if (q == 0) {
            int s = src[r];
            float a = part + s_n[s];
            float lr = (a >= 0.f) ? a : NEG_SLOPE * a;
            float xe = __expf(lr);
            ex[r] = xe;
            atomicAdd(denom + s, xe);
        }
    }
}

// e_weighted = (ex/denom[src]) * (e @ We^T); transposed MFMA, f32x4 nt-stores.
// We fragments converted from f32 in-kernel (16KB, L2-hot).
__global__ __launch_bounds__(256) void k4_mfma(
    const short* __restrict__ ebf, const float* __restrict__ We,
    const int* __restrict__ src, const float* __restrict__ denom,
    const float* __restrict__ ex, float* __restrict__ oute) {
    const int wave = threadIdx.x >> 6;
    const int lane = threadIdx.x & 63;
    const int l15  = lane & 15;
    const int lhi  = lane >> 4;
    const long base = (long)blockIdx.x * 256 + wave * 64;  // first edge row

    // A-fragments (We rows, converted): row = ct*16+l15, k = kt*32+lhi*8
    short8 Af[2][4];
    #pragma unroll
    for (int kt = 0; kt < 2; ++kt)
        #pragma unroll
        for (int ct = 0; ct < 4; ++ct) {
            const float* wrow = We + (ct * 16 + l15) * kEdgeIn + kt * 32 + lhi * 8;
            f32x4 w0 = *reinterpret_cast<const f32x4*>(wrow);
            f32x4 w1 = *reinterpret_cast<const f32x4*>(wrow + 4);
            short8 af;
            af[0] = f2bf(w0[0]); af[1] = f2bf(w0[1]); af[2] = f2bf(w0[2]); af[3] = f2bf(w0[3]);
            af[4] = f2bf(w1[0]); af[5] = f2bf(w1[1]); af[6] = f2bf(w1[2]); af[7] = f2bf(w1[3]);
            Af[kt][ct] = af;
        }

    f32x4 acc[4][4];
    #pragma unroll
    for (int m = 0; m < 4; ++m)
        #pragma unroll
        for (int n = 0; n < 4; ++n) acc[m][n] = (f32x4)(0.f);

    #pragma unroll
    for (int m = 0; m < 4; ++m) {
        const short* erow = ebf + (base + m * 16 + l15) * kEdgeIn;
        #pragma unroll
        for (int kt = 0; kt < 2; ++kt) {
            short8 bf = *reinterpret_cast<const short8*>(erow + kt * 32 + lhi * 8);
            #pragma unroll
            for (int ct = 0; ct < 4; ++ct)
                acc[m][ct] = __builtin_amdgcn_mfma_f32_16x16x32_bf16(
                    Af[kt][ct], bf, acc[m][ct], 0, 0, 0);
        }
    }

    // Transposed epilogue: lane owns edge (base+m*16+l15), channels ct*16+lhi*4+0..3.
    #pragma unroll
    for (int m = 0; m < 4; ++m) {
        const long edge = base + m * 16 + l15;
        int s = src[edge];
        float g = ex[edge] * __builtin_amdgcn_rcpf(denom[s]);
        #pragma unroll
        for (int ct = 0; ct < 4; ++ct) {
            f32x4 o = acc[m][ct] * g;
            __builtin_nontemporal_store(o,
                reinterpret_cast<f32x4*>(oute + edge * kEdgeOut + ct * 16 + lhi * 4));
        }
    }
}

extern "C" void kernel_launch(void* const* d_in, const int* in_sizes, int n_in,
                              void* d_out, int out_size, void* d_ws, size_t ws_size,
                              hipStream_t stream) {
    const float* h   = (const float*)d_in[0];
    const float* e   = (const float*)d_in[1];
    const float* Wn  = (const float*)d_in[2];
    const float* We  = (const float*)d_in[3];
    const float* Wa  = (const float*)d_in[4];
    const int*   src = (const int*)d_in[5];

    float* node_feat = (float*)d_out;
    float* oute      = (float*)d_out + (size_t)kNodes * kNodeOut;

    float* ws    = (float*)d_ws;
    float* s_n   = ws + kOffSn;
    float* denom = ws + kOffDenom;
    float* ex    = ws + kOffEx;
    short* ebf   = (short*)(ws + kOffEbf);

    k1_mfma<<<(kNodes + 63) / 64, 256, 0, stream>>>(h, Wn, Wa, node_feat, s_n, denom);
    kconv<<<kEdges / 64, 256, 0, stream>>>(e, We, Wa, src, s_n, denom, ex, ebf);
    k4_mfma<<<kEdges / 256, 256, 0, stream>>>(ebf, We, src, denom, ex, oute);
}

// Round 11
// 159.735 us; speedup vs baseline: 1.2392x; 1.2392x over previous
//
#include <hip/hip_runtime.h>

// WeightedAggEdge: node_feat = h@Wn^T; per-edge segment-softmax attention
// over fc_e(e) grouped by src node; outputs (node_feat, gamma * e_w).
//
// Round 11: exact round-6 structure (154.3us champion: k0 bf16 weight prep,
// k1 MFMA nodes, kconv fused stream+logit+atomic, k4 MFMA edges) with ONE
// change: transposed MFMA epilogues (swap A/B args; lane owns one row,
// 4 consecutive channels per reg) -> f32x4 stores, 3x fewer epilogue loads.

constexpr int kNodes   = 50000;
constexpr int kEdges   = 800000;
constexpr int kNodeIn  = 128;
constexpr int kNodeOut = 64;
constexpr int kEdgeIn  = 64;
constexpr int kEdgeOut = 64;
#define NEG_SLOPE 0.01f

typedef __attribute__((ext_vector_type(8))) short short8;   // 8 bf16 = 4 VGPRs
typedef __attribute__((ext_vector_type(4))) short short4v;  // 4 bf16 = 8 B
typedef __attribute__((ext_vector_type(4))) float f32x4;

// ws layout (float index):
//   [0, 64)              v = We^T @ Wa_e
//   [64, 50064)          s_n
//   [50064, 100064)      denom
//   [100064, 900064)     ex
//   [900064, 902112)     We_bf16 (4096 shorts)
//   [902112, 906208)     Wn_bf16 (8192 shorts)
//   [906240, +25.6M)     e_bf16  (kEdges*64 shorts = 102.4 MB)
constexpr int kOffV     = 0;
constexpr int kOffSn    = 64;
constexpr int kOffDenom = 50064;
constexpr int kOffEx    = 100064;
constexpr int kOffWeB   = 900064;
constexpr int kOffWnB   = 902112;
constexpr int kOffEbf   = 906240;

__device__ inline short f2bf(float x) {
    union { float f; unsigned u; } v; v.f = x;
    unsigned r = v.u + 0x7FFFu + ((v.u >> 16) & 1u);  // RNE
    return (short)(r >> 16);
}

// 48 blocks: 0..15 convert We (4096), 16..47 convert Wn (8192); block 0 also v.
__global__ void k0_prep(const float* __restrict__ We, const float* __restrict__ Wn,
                        const float* __restrict__ Wa,
                        float* __restrict__ v, short* __restrict__ Web,
                        short* __restrict__ Wnb) {
    int b = blockIdx.x, t = threadIdx.x;
    if (b == 0 && t < kEdgeIn) {
        float acc = 0.f;
        #pragma unroll
        for (int c = 0; c < kEdgeOut; ++c) acc = fmaf(Wa[c], We[c * kEdgeIn + t], acc);
        v[t] = acc;
    }
    if (b < 16) {
        int i = b * 256 + t;
        Web[i] = f2bf(We[i]);
    } else {
        int i = (b - 16) * 256 + t;
        Wnb[i] = f2bf(Wn[i]);
    }
}

// node_feat = h @ Wn^T via bf16 MFMA, TRANSPOSED (D' = Wn-tile x h^T):
// lane owns node n0+l15, channels ct*16 + lhi*4 + 0..3 -> f32x4 nt-stores.
// s_n via Wa-weighted partial + shfl_xor(16/32); denom zero-init.
__global__ __launch_bounds__(256) void k1_mfma(
    const float* __restrict__ h, const short* __restrict__ Wnb,
    const float* __restrict__ Wa, float* __restrict__ node_feat,
    float* __restrict__ s_n, float* __restrict__ denom) {
    const int lane = threadIdx.x & 63;
    const int l15  = lane & 15;
    const int lhi  = lane >> 4;
    const int n0   = blockIdx.x * 64 + (threadIdx.x >> 6) * 16;

    int gid = blockIdx.x * 256 + threadIdx.x;
    if (gid < kNodes) denom[gid] = 0.f;

    // A-fragments (Wn rows): row = ct*16+l15 (tile-local), k = kt*32+lhi*8
    short8 Af[4][4];
    #pragma unroll
    for (int kt = 0; kt < 4; ++kt)
        #pragma unroll
        for (int ct = 0; ct < 4; ++ct)
            Af[kt][ct] = *reinterpret_cast<const short8*>(
                Wnb + (ct * 16 + l15) * kNodeIn + kt * 32 + lhi * 8);

    const int  arow   = n0 + l15;
    const bool rv     = arow < kNodes;
    const float* hrow = h + (size_t)arow * kNodeIn;

    f32x4 acc[4];
    #pragma unroll
    for (int ct = 0; ct < 4; ++ct) acc[ct] = (f32x4)(0.f);

    #pragma unroll
    for (int kt = 0; kt < 4; ++kt) {
        short8 bf;  // B: col = node (l15), k slice
        if (rv) {
            f32x4 t0 = *reinterpret_cast<const f32x4*>(hrow + kt * 32 + lhi * 8);
            f32x4 t1 = *reinterpret_cast<const f32x4*>(hrow + kt * 32 + lhi * 8 + 4);
            bf[0] = f2bf(t0[0]); bf[1] = f2bf(t0[1]); bf[2] = f2bf(t0[2]); bf[3] = f2bf(t0[3]);
            bf[4] = f2bf(t1[0]); bf[5] = f2bf(t1[1]); bf[6] = f2bf(t1[2]); bf[7] = f2bf(t1[3]);
        } else {
            #pragma unroll
            for (int j = 0; j < 8; ++j) bf[j] = 0;
        }
        #pragma unroll
        for (int ct = 0; ct < 4; ++ct)
            acc[ct] = __builtin_amdgcn_mfma_f32_16x16x32_bf16(Af[kt][ct], bf, acc[ct], 0, 0, 0);
    }

    // Transposed epilogue.
    float part = 0.f;
    #pragma unroll
    for (int ct = 0; ct < 4; ++ct) {
        f32x4 wa4 = *reinterpret_cast<const f32x4*>(Wa + 64 + ct * 16 + lhi * 4);
        part = fmaf(wa4[0], acc[ct][0], part);
        part = fmaf(wa4[1], acc[ct][1], part);
        part = fmaf(wa4[2], acc[ct][2], part);
        part = fmaf(wa4[3], acc[ct][3], part);
        if (rv)
            __builtin_nontemporal_store(acc[ct],
                reinterpret_cast<f32x4*>(node_feat + (size_t)arow * kNodeOut + ct * 16 + lhi * 4));
    }
    part += __shfl_xor(part, 16, 64);
    part += __shfl_xor(part, 32, 64);
    if (rv && lhi == 0) s_n[arow] = part;
}

// Coalesced streaming pass over e: 64 rows per block (4 iters x 16 rows).
// Thread t handles float4 #(t&15) of row; shfl-reduce dot; lane q==0 finishes
// the logit (s_n gather, leaky, exp), stores ex, atomicAdd denom.
// bf16 convert -> 8B store to ebf.
__global__ __launch_bounds__(256) void kconv(
    const float* __restrict__ e, const float* __restrict__ v,
    const int* __restrict__ src, const float* __restrict__ s_n,
    float* __restrict__ denom, float* __restrict__ ex,
    short* __restrict__ ebf) {
    const int t   = threadIdx.x;
    const int q   = t & 15;
    const int rlo = t >> 4;
    const long base = (long)blockIdx.x * 64;

    f32x4 vv = *(reinterpret_cast<const f32x4*>(v) + q);

    #pragma unroll
    for (int it = 0; it < 4; ++it) {
        long r = base + it * 16 + rlo;
        f32x4 d = *(reinterpret_cast<const f32x4*>(e + r * kEdgeIn) + q);
        float part = d[0] * vv[0] + d[1] * vv[1] + d[2] * vv[2] + d[3] * vv[3];
        part += __shfl_xor(part, 1, 64);
        part += __shfl_xor(part, 2, 64);
        part += __shfl_xor(part, 4, 64);
        part += __shfl_xor(part, 8, 64);
        short4v o;
        o[0] = f2bf(d[0]); o[1] = f2bf(d[1]); o[2] = f2bf(d[2]); o[3] = f2bf(d[3]);
        *reinterpret_cast<short4v*>(ebf + r * kEdgeIn + q * 4) = o;
        if (q == 0) {
            int s = src[r];
            float a = part + s_n[s];
            float lr = (a >= 0.f) ? a : NEG_SLOPE * a;
            float xe = __expf(lr);
            ex[r] = xe;
            atomicAdd(denom + s, xe);
        }
    }
}

// e_weighted = (ex/denom[src]) * (e @ We^T), TRANSPOSED MFMA:
// lane owns edge base+m*16+l15, channels ct*16+lhi*4+0..3 -> f32x4 nt-stores.
__global__ __launch_bounds__(256) void k4_mfma(
    const short* __restrict__ ebf, const short* __restrict__ Web,
    const int* __restrict__ src, const float* __restrict__ denom,
    const float* __restrict__ ex, float* __restrict__ oute) {
    const int wave = threadIdx.x >> 6;
    const int lane = threadIdx.x & 63;
    const int l15  = lane & 15;
    const int lhi  = lane >> 4;
    const long base = (long)blockIdx.x * 256 + wave * 64;  // first edge row

    // A-fragments (We rows): row = ct*16+l15 (tile-local), k = kt*32+lhi*8
    short8 Af[2][4];
    #pragma unroll
    for (int kt = 0; kt < 2; ++kt)
        #pragma unroll
        for (int ct = 0; ct < 4; ++ct)
            Af[kt][ct] = *reinterpret_cast<const short8*>(
                Web + (ct * 16 + l15) * kEdgeIn + kt * 32 + lhi * 8);

    f32x4 acc[4][4];
    #pragma unroll
    for (int m = 0; m < 4; ++m)
        #pragma unroll
        for (int n = 0; n < 4; ++n) acc[m][n] = (f32x4)(0.f);

    #pragma unroll
    for (int m = 0; m < 4; ++m) {
        const short* erow = ebf + (base + m * 16 + l15) * kEdgeIn;
        #pragma unroll
        for (int kt = 0; kt < 2; ++kt) {
            short8 bf = *reinterpret_cast<const short8*>(erow + kt * 32 + lhi * 8);
            #pragma unroll
            for (int ct = 0; ct < 4; ++ct)
                acc[m][ct] = __builtin_amdgcn_mfma_f32_16x16x32_bf16(
                    Af[kt][ct], bf, acc[m][ct], 0, 0, 0);
        }
    }

    // Transposed epilogue: 3 scalar gathers + 4 f32x4 nt-stores per m.
    #pragma unroll
    for (int m = 0; m < 4; ++m) {
        const long edge = base + m * 16 + l15;
        int s = src[edge];
        float g = ex[edge] * __builtin_amdgcn_rcpf(denom[s]);
        #pragma unroll
        for (int ct = 0; ct < 4; ++ct) {
            f32x4 o = acc[m][ct] * g;
            __builtin_nontemporal_store(o,
                reinterpret_cast<f32x4*>(oute + edge * kEdgeOut + ct * 16 + lhi * 4));
        }
    }
}

extern "C" void kernel_launch(void* const* d_in, const int* in_sizes, int n_in,
                              void* d_out, int out_size, void* d_ws, size_t ws_size,
                              hipStream_t stream) {
    const float* h   = (const float*)d_in[0];
    const float* e   = (const float*)d_in[1];
    const float* Wn  = (const float*)d_in[2];
    const float* We  = (const float*)d_in[3];
    const float* Wa  = (const float*)d_in[4];
    const int*   src = (const int*)d_in[5];

    float* node_feat = (float*)d_out;
    float* oute      = (float*)d_out + (size_t)kNodes * kNodeOut;

    float* ws    = (float*)d_ws;
    float* v     = ws + kOffV;
    float* s_n   = ws + kOffSn;
    float* denom = ws + kOffDenom;
    float* ex    = ws + kOffEx;
    short* Web   = (short*)(ws + kOffWeB);
    short* Wnb   = (short*)(ws + kOffWnB);
    short* ebf   = (short*)(ws + kOffEbf);

    k0_prep<<<48, 256, 0, stream>>>(We, Wn, Wa, v, Web, Wnb);
    k1_mfma<<<(kNodes + 63) / 64, 256, 0, stream>>>(h, Wnb, Wa, node_feat, s_n, denom);
    kconv<<<kEdges / 64, 256, 0, stream>>>(e, v, src, s_n, denom, ex, ebf);
    k4_mfma<<<kEdges / 256, 256, 0, stream>>>(ebf, Web, src, denom, ex, oute);
}

// Round 12
// 159.393 us; speedup vs baseline: 1.2419x; 1.0021x over previous
//
#include <hip/hip_runtime.h>

// WeightedAggEdge: node_feat = h@Wn^T; per-edge segment-softmax attention
// over fc_e(e) grouped by src node; outputs (node_feat, gamma * e_w).
//
// Round 12 restructure: logit av = (e@We^T). Wa_e, so the MFMA moves into
// the e-stream kernel (kfused), which stores u = exp(leaky(logit)) * e_w in
// bf16. kscale is then a pure coalesced stream: oute = u * rcp(denom[src]).
// Same total bytes as R6, but 313 MB now moves in a trivial max-BW kernel
// and the MFMA hides under the compulsory e read. ex/ebf/v arrays deleted.

constexpr int kNodes   = 50000;
constexpr int kEdges   = 800000;
constexpr int kNodeIn  = 128;
constexpr int kNodeOut = 64;
constexpr int kEdgeIn  = 64;
constexpr int kEdgeOut = 64;
#define NEG_SLOPE 0.01f

typedef __attribute__((ext_vector_type(8))) short short8;   // 8 bf16 = 4 VGPRs
typedef __attribute__((ext_vector_type(4))) short short4v;  // 4 bf16 = 8 B
typedef __attribute__((ext_vector_type(4))) float f32x4;

// ws layout (float index), 16B-aligned:
//   [0, 50000)           s_n
//   [50048, 100048)      denom
//   [100096, 102144)     We_bf16 (4096 shorts)
//   [102144, 106240)     Wn_bf16 (8192 shorts)
//   [106240, +25.6M)     u_bf16 (kEdges*64 shorts = 102.4 MB)
constexpr int kOffSn    = 0;
constexpr int kOffDenom = 50048;
constexpr int kOffWeB   = 100096;
constexpr int kOffWnB   = 102144;
constexpr int kOffUbf   = 106240;

__device__ inline short f2bf(float x) {
    union { float f; unsigned u; } v; v.f = x;
    unsigned r = v.u + 0x7FFFu + ((v.u >> 16) & 1u);  // RNE
    return (short)(r >> 16);
}
__device__ inline float bf2f(short x) {
    union { unsigned u; float f; } v;
    v.u = ((unsigned)(unsigned short)x) << 16;
    return v.f;
}

// 48 blocks: 0..15 convert We (4096), 16..47 convert Wn (8192).
__global__ void k0_prep(const float* __restrict__ We, const float* __restrict__ Wn,
                        short* __restrict__ Web, short* __restrict__ Wnb) {
    int b = blockIdx.x, t = threadIdx.x;
    if (b < 16) {
        int i = b * 256 + t;
        Web[i] = f2bf(We[i]);
    } else {
        int i = (b - 16) * 256 + t;
        Wnb[i] = f2bf(Wn[i]);
    }
}

// node_feat = h @ Wn^T via bf16 MFMA; one wave = 16 nodes. (R6-exact)
// s_n[n] = dot(Wa[64:128], node_feat[n]) via 16-lane shfl reduce; denom init.
__global__ __launch_bounds__(256) void k1_mfma(
    const float* __restrict__ h, const short* __restrict__ Wnb,
    const float* __restrict__ Wa, float* __restrict__ node_feat,
    float* __restrict__ s_n, float* __restrict__ denom) {
    const int lane = threadIdx.x & 63;
    const int l15  = lane & 15;
    const int lhi  = lane >> 4;
    const int n0   = blockIdx.x * 64 + (threadIdx.x >> 6) * 16;

    int gid = blockIdx.x * 256 + threadIdx.x;
    if (gid < kNodes) denom[gid] = 0.f;

    short8 Bf[4][4];
    #pragma unroll
    for (int kt = 0; kt < 4; ++kt)
        #pragma unroll
        for (int ct = 0; ct < 4; ++ct)
            Bf[kt][ct] = *reinterpret_cast<const short8*>(
                Wnb + (ct * 16 + l15) * kNodeIn + kt * 32 + lhi * 8);

    const int  arow   = n0 + l15;
    const bool avalid = arow < kNodes;
    const float* hrow = h + (size_t)arow * kNodeIn;

    f32x4 acc[4];
    #pragma unroll
    for (int ct = 0; ct < 4; ++ct) acc[ct] = (f32x4)(0.f);

    #pragma unroll
    for (int kt = 0; kt < 4; ++kt) {
        short8 af;
        if (avalid) {
            f32x4 t0 = *reinterpret_cast<const f32x4*>(hrow + kt * 32 + lhi * 8);
            f32x4 t1 = *reinterpret_cast<const f32x4*>(hrow + kt * 32 + lhi * 8 + 4);
            af[0] = f2bf(t0[0]); af[1] = f2bf(t0[1]); af[2] = f2bf(t0[2]); af[3] = f2bf(t0[3]);
            af[4] = f2bf(t1[0]); af[5] = f2bf(t1[1]); af[6] = f2bf(t1[2]); af[7] = f2bf(t1[3]);
        } else {
            #pragma unroll
            for (int j = 0; j < 8; ++j) af[j] = 0;
        }
        #pragma unroll
        for (int ct = 0; ct < 4; ++ct)
            acc[ct] = __builtin_amdgcn_mfma_f32_16x16x32_bf16(af, Bf[kt][ct], acc[ct], 0, 0, 0);
    }

    float wa[4];
    #pragma unroll
    for (int ct = 0; ct < 4; ++ct) wa[ct] = Wa[64 + ct * 16 + l15];

    #pragma unroll
    for (int reg = 0; reg < 4; ++reg) {
        int r = n0 + lhi * 4 + reg;
        bool rv = r < kNodes;
        float part = 0.f;
        #pragma unroll
        for (int ct = 0; ct < 4; ++ct) part = fmaf(wa[ct], acc[ct][reg], part);
        if (rv) {
            #pragma unroll
            for (int ct = 0; ct < 4; ++ct)
                __builtin_nontemporal_store(acc[ct][reg],
                    node_feat + (size_t)r * kNodeOut + ct * 16 + l15);
        }
        part += __shfl_xor(part, 1, 64);
        part += __shfl_xor(part, 2, 64);
        part += __shfl_xor(part, 4, 64);
        part += __shfl_xor(part, 8, 64);
        if (rv && l15 == 0) s_n[r] = part;
    }
}

// Fused e-stream: per wave, 64 edges (4 m-tiles). Transposed MFMA
// (lane owns edge l15, channels ct*16+lhi*4+0..3):
//   e_w = e @ We^T (bf16 MFMA, f32 acc)
//   av  = dot(e_w, Wa_e) via per-lane partial + shfl_xor(16/32)
//   xe  = exp(leaky(av + s_n[src]))  (known by all 4 lhi lanes)
//   u   = xe * e_w  -> bf16 store; atomicAdd(denom[src], xe) on lhi==0.
__global__ __launch_bounds__(256) void kfused(
    const float* __restrict__ e, const short* __restrict__ Web,
    const float* __restrict__ Wa, const int* __restrict__ src,
    const float* __restrict__ s_n, float* __restrict__ denom,
    short* __restrict__ ubf) {
    const int wave = threadIdx.x >> 6;
    const int lane = threadIdx.x & 63;
    const int l15  = lane & 15;
    const int lhi  = lane >> 4;
    const long base = (long)blockIdx.x * 256 + wave * 64;

    // A-fragments (We rows): row = ct*16+l15 (tile-local), k = kt*32+lhi*8
    short8 Af[2][4];
    #pragma unroll
    for (int kt = 0; kt < 2; ++kt)
        #pragma unroll
        for (int ct = 0; ct < 4; ++ct)
            Af[kt][ct] = *reinterpret_cast<const short8*>(
                Web + (ct * 16 + l15) * kEdgeIn + kt * 32 + lhi * 8);

    // Wa_e fragment for this lane's 16 channels.
    f32x4 wa4[4];
    #pragma unroll
    for (int ct = 0; ct < 4; ++ct)
        wa4[ct] = *reinterpret_cast<const f32x4*>(Wa + ct * 16 + lhi * 4);

    #pragma unroll
    for (int m = 0; m < 4; ++m) {
        const long edge = base + m * 16 + l15;
        const float* erow = e + edge * kEdgeIn;

        f32x4 t0 = *reinterpret_cast<const f32x4*>(erow + lhi * 8);
        f32x4 t1 = *reinterpret_cast<const f32x4*>(erow + lhi * 8 + 4);
        f32x4 t2 = *reinterpret_cast<const f32x4*>(erow + 32 + lhi * 8);
        f32x4 t3 = *reinterpret_cast<const f32x4*>(erow + 32 + lhi * 8 + 4);
        short8 bf0, bf1;
        bf0[0] = f2bf(t0[0]); bf0[1] = f2bf(t0[1]); bf0[2] = f2bf(t0[2]); bf0[3] = f2bf(t0[3]);
        bf0[4] = f2bf(t1[0]); bf0[5] = f2bf(t1[1]); bf0[6] = f2bf(t1[2]); bf0[7] = f2bf(t1[3]);
        bf1[0] = f2bf(t2[0]); bf1[1] = f2bf(t2[1]); bf1[2] = f2bf(t2[2]); bf1[3] = f2bf(t2[3]);
        bf1[4] = f2bf(t3[0]); bf1[5] = f2bf(t3[1]); bf1[6] = f2bf(t3[2]); bf1[7] = f2bf(t3[3]);

        f32x4 acc[4];
        #pragma unroll
        for (int ct = 0; ct < 4; ++ct) acc[ct] = (f32x4)(0.f);
        #pragma unroll
        for (int ct = 0; ct < 4; ++ct)
            acc[ct] = __builtin_amdgcn_mfma_f32_16x16x32_bf16(Af[0][ct], bf0, acc[ct], 0, 0, 0);
        #pragma unroll
        for (int ct = 0; ct < 4; ++ct)
            acc[ct] = __builtin_amdgcn_mfma_f32_16x16x32_bf16(Af[1][ct], bf1, acc[ct], 0, 0, 0);

        // Logit for this edge.
        float part = 0.f;
        #pragma unroll
        for (int ct = 0; ct < 4; ++ct) {
            part = fmaf(wa4[ct][0], acc[ct][0], part);
            part = fmaf(wa4[ct][1], acc[ct][1], part);
            part = fmaf(wa4[ct][2], acc[ct][2], part);
            part = fmaf(wa4[ct][3], acc[ct][3], part);
        }
        part += __shfl_xor(part, 16, 64);
        part += __shfl_xor(part, 32, 64);

        int s = src[edge];
        float a  = part + s_n[s];
        float lr = (a >= 0.f) ? a : NEG_SLOPE * a;
        float xe = __expf(lr);

        // u = xe * e_w -> bf16.
        #pragma unroll
        for (int ct = 0; ct < 4; ++ct) {
            f32x4 uv = acc[ct] * xe;
            short4v o;
            o[0] = f2bf(uv[0]); o[1] = f2bf(uv[1]); o[2] = f2bf(uv[2]); o[3] = f2bf(uv[3]);
            *reinterpret_cast<short4v*>(ubf + edge * kEdgeOut + ct * 16 + lhi * 4) = o;
        }
        if (lhi == 0) atomicAdd(denom + s, xe);
    }
}

// Pure stream: oute = u * rcp(denom[src]).  Thread owns 4 channels (8B in,
// 16B out); 16 consecutive threads cover one row -> fully coalesced.
__global__ __launch_bounds__(256) void kscale(
    const short* __restrict__ ubf, const int* __restrict__ src,
    const float* __restrict__ denom, float* __restrict__ oute) {
    long c = (long)blockIdx.x * 256 + threadIdx.x;
    long r = c >> 4;
    int  q = (int)(c & 15);
    short4v u4 = *reinterpret_cast<const short4v*>(ubf + r * kEdgeOut + q * 4);
    int s = src[r];
    float g = __builtin_amdgcn_rcpf(denom[s]);
    f32x4 o;
    o[0] = bf2f(u4[0]) * g;
    o[1] = bf2f(u4[1]) * g;
    o[2] = bf2f(u4[2]) * g;
    o[3] = bf2f(u4[3]) * g;
    __builtin_nontemporal_store(o,
        reinterpret_cast<f32x4*>(oute + r * kEdgeOut + q * 4));
}

extern "C" void kernel_launch(void* const* d_in, const int* in_sizes, int n_in,
                              void* d_out, int out_size, void* d_ws, size_t ws_size,
                              hipStream_t stream) {
    const float* h   = (const float*)d_in[0];
    const float* e   = (const float*)d_in[1];
    const float* Wn  = (const float*)d_in[2];
    const float* We  = (const float*)d_in[3];
    const float* Wa  = (const float*)d_in[4];
    const int*   src = (const int*)d_in[5];

    float* node_feat = (float*)d_out;
    float* oute      = (float*)d_out + (size_t)kNodes * kNodeOut;

    float* ws    = (float*)d_ws;
    float* s_n   = ws + kOffSn;
    float* denom = ws + kOffDenom;
    short* Web   = (short*)(ws + kOffWeB);
    short* Wnb   = (short*)(ws + kOffWnB);
    short* ubf   = (short*)(ws + kOffUbf);

    k0_prep<<<48, 256, 0, stream>>>(We, Wn, Web, Wnb);
    k1_mfma<<<(kNodes + 63) / 64, 256, 0, stream>>>(h, Wnb, Wa, node_feat, s_n, denom);
    kfused<<<kEdges / 256, 256, 0, stream>>>(e, Web, Wa, src, s_n, denom, ubf);
    kscale<<<(kEdges * (kEdgeOut / 4) + 255) / 256, 256, 0, stream>>>(ubf, src, denom, oute);
}

// Round 13
// 154.320 us; speedup vs baseline: 1.2827x; 1.0329x over previous
//
#include <hip/hip_runtime.h>

// WeightedAggEdge: node_feat = h@Wn^T; per-edge segment-softmax attention
// over fc_e(e) grouped by src node; outputs (node_feat, gamma * e_w).
//
// FINAL (round-6 champion, 154.3us): k0 bf16 weight prep; k1 MFMA nodes
// (+s_n reduce, denom init); kconv coalesced e-stream (bf16 spill + fused
// logit/exp/atomic tail on lane q==0); k4 MFMA edges with fused gamma.
// All later variants (NT hints, XCD atomic replicas, transposed epilogues,
// MFMA-in-stream restructure) measured neutral-to-negative; this structure
// is within ~7% of the practical mixed-stream floor (~144us) for the
// compulsory ~614 MB of traffic.

constexpr int kNodes   = 50000;
constexpr int kEdges   = 800000;
constexpr int kNodeIn  = 128;
constexpr int kNodeOut = 64;
constexpr int kEdgeIn  = 64;
constexpr int kEdgeOut = 64;
#define NEG_SLOPE 0.01f

typedef __attribute__((ext_vector_type(8))) short short8;   // 8 bf16 = 4 VGPRs
typedef __attribute__((ext_vector_type(4))) short short4v;  // 4 bf16 = 8 B
typedef __attribute__((ext_vector_type(4))) float f32x4;

// ws layout (float index):
//   [0, 64)              v = We^T @ Wa_e
//   [64, 50064)          s_n
//   [50064, 100064)      denom
//   [100064, 900064)     ex
//   [900064, 902112)     We_bf16 (4096 shorts)
//   [902112, 906208)     Wn_bf16 (8192 shorts)
//   [906240, +25.6M)     e_bf16  (kEdges*64 shorts = 102.4 MB)
constexpr int kOffV     = 0;
constexpr int kOffSn    = 64;
constexpr int kOffDenom = 50064;
constexpr int kOffEx    = 100064;
constexpr int kOffWeB   = 900064;
constexpr int kOffWnB   = 902112;
constexpr int kOffEbf   = 906240;

__device__ inline short f2bf(float x) {
    union { float f; unsigned u; } v; v.f = x;
    unsigned r = v.u + 0x7FFFu + ((v.u >> 16) & 1u);  // RNE
    return (short)(r >> 16);
}

// 48 blocks: 0..15 convert We (4096), 16..47 convert Wn (8192); block 0 also v.
__global__ void k0_prep(const float* __restrict__ We, const float* __restrict__ Wn,
                        const float* __restrict__ Wa,
                        float* __restrict__ v, short* __restrict__ Web,
                        short* __restrict__ Wnb) {
    int b = blockIdx.x, t = threadIdx.x;
    if (b == 0 && t < kEdgeIn) {
        float acc = 0.f;
        #pragma unroll
        for (int c = 0; c < kEdgeOut; ++c) acc = fmaf(Wa[c], We[c * kEdgeIn + t], acc);
        v[t] = acc;
    }
    if (b < 16) {
        int i = b * 256 + t;
        Web[i] = f2bf(We[i]);
    } else {
        int i = (b - 16) * 256 + t;
        Wnb[i] = f2bf(Wn[i]);
    }
}

// node_feat = h @ Wn^T via bf16 MFMA; one wave = 16 nodes.
// Also: s_n[n] = dot(Wa[64:128], node_feat[n]) via 16-lane shfl reduce; denom init.
__global__ __launch_bounds__(256) void k1_mfma(
    const float* __restrict__ h, const short* __restrict__ Wnb,
    const float* __restrict__ Wa, float* __restrict__ node_feat,
    float* __restrict__ s_n, float* __restrict__ denom) {
    const int lane = threadIdx.x & 63;
    const int l15  = lane & 15;
    const int lhi  = lane >> 4;
    const int n0   = blockIdx.x * 64 + (threadIdx.x >> 6) * 16;

    int gid = blockIdx.x * 256 + threadIdx.x;
    if (gid < kNodes) denom[gid] = 0.f;

    short8 Bf[4][4];
    #pragma unroll
    for (int kt = 0; kt < 4; ++kt)
        #pragma unroll
        for (int ct = 0; ct < 4; ++ct)
            Bf[kt][ct] = *reinterpret_cast<const short8*>(
                Wnb + (ct * 16 + l15) * kNodeIn + kt * 32 + lhi * 8);

    const int  arow   = n0 + l15;
    const bool avalid = arow < kNodes;
    const float* hrow = h + (size_t)arow * kNodeIn;

    f32x4 acc[4];
    #pragma unroll
    for (int ct = 0; ct < 4; ++ct) acc[ct] = (f32x4)(0.f);

    #pragma unroll
    for (int kt = 0; kt < 4; ++kt) {
        short8 af;
        if (avalid) {
            f32x4 t0 = *reinterpret_cast<const f32x4*>(hrow + kt * 32 + lhi * 8);
            f32x4 t1 = *reinterpret_cast<const f32x4*>(hrow + kt * 32 + lhi * 8 + 4);
            af[0] = f2bf(t0[0]); af[1] = f2bf(t0[1]); af[2] = f2bf(t0[2]); af[3] = f2bf(t0[3]);
            af[4] = f2bf(t1[0]); af[5] = f2bf(t1[1]); af[6] = f2bf(t1[2]); af[7] = f2bf(t1[3]);
        } else {
            #pragma unroll
            for (int j = 0; j < 8; ++j) af[j] = 0;
        }
        #pragma unroll
        for (int ct = 0; ct < 4; ++ct)
            acc[ct] = __builtin_amdgcn_mfma_f32_16x16x32_bf16(af, Bf[kt][ct], acc[ct], 0, 0, 0);
    }

    float wa[4];
    #pragma unroll
    for (int ct = 0; ct < 4; ++ct) wa[ct] = Wa[64 + ct * 16 + l15];

    #pragma unroll
    for (int reg = 0; reg < 4; ++reg) {
        int r = n0 + lhi * 4 + reg;
        bool rv = r < kNodes;
        float part = 0.f;
        #pragma unroll
        for (int ct = 0; ct < 4; ++ct) part = fmaf(wa[ct], acc[ct][reg], part);
        if (rv) {
            #pragma unroll
            for (int ct = 0; ct < 4; ++ct)
                __builtin_nontemporal_store(acc[ct][reg],
                    node_feat + (size_t)r * kNodeOut + ct * 16 + l15);
        }
        part += __shfl_xor(part, 1, 64);
        part += __shfl_xor(part, 2, 64);
        part += __shfl_xor(part, 4, 64);
        part += __shfl_xor(part, 8, 64);
        if (rv && l15 == 0) s_n[r] = part;
    }
}

// Coalesced streaming pass over e: 64 rows per block (4 iters x 16 rows).
// Thread t handles float4 #(t&15) of row; shfl-reduce dot; lane q==0 finishes
// the logit (s_n gather, leaky, exp), stores ex, atomicAdd denom.
// bf16 convert -> 8B store to ebf.
__global__ __launch_bounds__(256) void kconv(
    const float* __restrict__ e, const float* __restrict__ v,
    const int* __restrict__ src, const float* __restrict__ s_n,
    float* __restrict__ denom, float* __restrict__ ex,
    short* __restrict__ ebf) {
    const int t   = threadIdx.x;
    const int q   = t & 15;
    const int rlo = t >> 4;
    const long base = (long)blockIdx.x * 64;

    f32x4 vv = *(reinterpret_cast<const f32x4*>(v) + q);

    #pragma unroll
    for (int it = 0; it < 4; ++it) {
        long r = base + it * 16 + rlo;
        f32x4 d = *(reinterpret_cast<const f32x4*>(e + r * kEdgeIn) + q);
        float part = d[0] * vv[0] + d[1] * vv[1] + d[2] * vv[2] + d[3] * vv[3];
        part += __shfl_xor(part, 1, 64);
        part += __shfl_xor(part, 2, 64);
        part += __shfl_xor(part, 4, 64);
        part += __shfl_xor(part, 8, 64);
        short4v o;
        o[0] = f2bf(d[0]); o[1] = f2bf(d[1]); o[2] = f2bf(d[2]); o[3] = f2bf(d[3]);
        *reinterpret_cast<short4v*>(ebf + r * kEdgeIn + q * 4) = o;
        if (q == 0) {
            int s = src[r];
            float a = part + s_n[s];
            float lr = (a >= 0.f) ? a : NEG_SLOPE * a;
            float xe = __expf(lr);
            ex[r] = xe;
            atomicAdd(denom + s, xe);
        }
    }
}

// e_weighted = (ex/denom[src]) * (e @ We^T); A-fragments read directly as bf16.
__global__ __launch_bounds__(256) void k4_mfma(
    const short* __restrict__ ebf, const short* __restrict__ Web,
    const int* __restrict__ src, const float* __restrict__ denom,
    const float* __restrict__ ex, float* __restrict__ oute) {
    const int wave = threadIdx.x >> 6;
    const int lane = threadIdx.x & 63;
    const int l15  = lane & 15;
    const int lhi  = lane >> 4;
    const long base = (long)blockIdx.x * 256 + wave * 64;  // first edge row

    short8 Bf[2][4];
    #pragma unroll
    for (int kt = 0; kt < 2; ++kt)
        #pragma unroll
        for (int ct = 0; ct < 4; ++ct)
            Bf[kt][ct] = *reinterpret_cast<const short8*>(
                Web + (ct * 16 + l15) * kEdgeIn + kt * 32 + lhi * 8);

    f32x4 acc[4][4];
    #pragma unroll
    for (int m = 0; m < 4; ++m)
        #pragma unroll
        for (int n = 0; n < 4; ++n) acc[m][n] = (f32x4)(0.f);

    #pragma unroll
    for (int m = 0; m < 4; ++m) {
        const short* erow = ebf + (base + m * 16 + l15) * kEdgeIn;
        #pragma unroll
        for (int kt = 0; kt < 2; ++kt) {
            short8 af = *reinterpret_cast<const short8*>(erow + kt * 32 + lhi * 8);
            #pragma unroll
            for (int ct = 0; ct < 4; ++ct)
                acc[m][ct] = __builtin_amdgcn_mfma_f32_16x16x32_bf16(
                    af, Bf[kt][ct], acc[m][ct], 0, 0, 0);
        }
    }

    // Epilogue: D col = ct*16+l15, row = lhi*4 + reg. gamma = ex * rcp(denom[src]).
    #pragma unroll
    for (int m = 0; m < 4; ++m) {
        const long r0 = base + m * 16 + lhi * 4;
        float4 exv = *reinterpret_cast<const float4*>(ex + r0);
        int4   sv  = *reinterpret_cast<const int4*>(src + r0);
        float ga[4];
        ga[0] = exv.x * __builtin_amdgcn_rcpf(denom[sv.x]);
        ga[1] = exv.y * __builtin_amdgcn_rcpf(denom[sv.y]);
        ga[2] = exv.z * __builtin_amdgcn_rcpf(denom[sv.z]);
        ga[3] = exv.w * __builtin_amdgcn_rcpf(denom[sv.w]);
        #pragma unroll
        for (int reg = 0; reg < 4; ++reg) {
            float gv = ga[reg];
            #pragma unroll
            for (int ct = 0; ct < 4; ++ct)
                __builtin_nontemporal_store(acc[m][ct][reg] * gv,
                    oute + (r0 + reg) * kEdgeOut + ct * 16 + l15);
        }
    }
}

extern "C" void kernel_launch(void* const* d_in, const int* in_sizes, int n_in,
                              void* d_out, int out_size, void* d_ws, size_t ws_size,
                              hipStream_t stream) {
    const float* h   = (const float*)d_in[0];
    const float* e   = (const float*)d_in[1];
    const float* Wn  = (const float*)d_in[2];
    const float* We  = (const float*)d_in[3];
    const float* Wa  = (const float*)d_in[4];
    const int*   src = (const int*)d_in[5];

    float* node_feat = (float*)d_out;
    float* oute      = (float*)d_out + (size_t)kNodes * kNodeOut;

    float* ws    = (float*)d_ws;
    float* v     = ws + kOffV;
    float* s_n   = ws + kOffSn;
    float* denom = ws + kOffDenom;
    float* ex    = ws + kOffEx;
    short* Web   = (short*)(ws + kOffWeB);
    short* Wnb   = (short*)(ws + kOffWnB);
    short* ebf   = (short*)(ws + kOffEbf);

    k0_prep<<<48, 256, 0, stream>>>(We, Wn, Wa, v, Web, Wnb);
    k1_mfma<<<(kNodes + 63) / 64, 256, 0, stream>>>(h, Wnb, Wa, node_feat, s_n, denom);
    kconv<<<kEdges / 64, 256, 0, stream>>>(e, v, src, s_n, denom, ex, ebf);
    k4_mfma<<<kEdges / 256, 256, 0, stream>>>(ebf, Web, src, denom, ex, oute);
}